// Round 7
// baseline (665.080 us; speedup 1.0000x reference)
//
#include <hip/hip_runtime.h>
#include <math.h>

// RNN_197568496340: 6-layer ReLU RNN (T=1024,B=2048,IN=2,H=20) + FC(20->2) + log_softmax.
//
// R7: LDS-pipe-bound fix. R4-R6 all ran 8 waves/CU x ~11 ds_read_b128/step
// (~1080 cyc/step on the CU-shared LDS pipe = the measured 1325-cyc step).
// Changes:
//  - rows/lane 2->4 (160 weight floats/lane), 2 batch elems per wave ->
//    1024 blocks = 4 waves/CU: per-CU LDS insts/step halved (~560 cyc).
//  - amdgpu_waves_per_eu(1,1): 1 wave/SIMD -> 512-reg budget, no parking.
//  - Head = role 30 = (l=6,g=0) via role/5,role%5 -- naturally uniform.
//    Head reads slot6 (h5) as "input" with padded fcw, slot7 (zeros, never
//    written) as "recurrent"; diverges only at the epilogue.
//  - x staging lanes 62/63 (c=0/1): parity-unrolled 2-register ring; each
//    global load is consumed 2 steps (~1100 cyc) after issue.
//  - LDS: 8 slots x 20 words x 2 parities x 2 batch = 640 words. Slot
//    stride 20 -> the 7 active slots per read hit disjoint bank quads;
//    c0/c1 pairs are 2-way (free, m136).

#define TT 1024
#define BB 2048
#define HH 20
#define SLOTW 20
#define CBATCH 160              // words per (parity, c): 8 slots * 20
#define PARW 320                // words per parity
#define LDSW 640
#define NSTEPS (TT + 6)         // 1030, even

// ws layout (floats)
#define WS_WH   0               // WH_pad [7][20][20]: l=0..5 Whh, l=6 zeros
#define WS_WI   2800            // WI_pad [7][20][20]: l=0 Wih0 padded, 1..5 Wih, 6 fcw padded
#define WS_BIAS 5600            // Bias   [32][4]: role<30 bih+bhh, 30 fcb-padded, 31 zeros

__global__ void stage_ws(const float* __restrict__ Wih0,
                         const float* __restrict__ Wih,
                         const float* __restrict__ Whh,
                         const float* __restrict__ bih,
                         const float* __restrict__ bhh,
                         const float* __restrict__ fcw,
                         const float* __restrict__ fcb,
                         float* __restrict__ ws) {
    const int i = threadIdx.x + blockIdx.x * blockDim.x;
    if (i < 2800) {
        const int l = i / 400, r = i % 400, j = r / 20, k = r % 20;
        ws[WS_WH + i] = (l < 6) ? Whh[l * 400 + r] : 0.f;
        float v;
        if (l == 0)     v = (k < 2) ? Wih0[j * 2 + k] : 0.f;
        else if (l < 6) v = Wih[(l - 1) * 400 + r];
        else            v = (j < 2) ? fcw[j * 20 + k] : 0.f;
        ws[WS_WI + i] = v;
    }
    if (i < 128) {
        const int role = i >> 2, e = i & 3;
        float v = 0.f;
        if (role < 30) {
            const int l = role / 5, jj = 4 * (role % 5) + e;
            v = bih[l * 20 + jj] + bhh[l * 20 + jj];
        } else if (role == 30) {
            v = (e < 2) ? fcb[e] : 0.f;
        }
        ws[WS_BIAS + i] = v;
    }
}

__device__ __forceinline__ float dot5(const float4 w[5], const float4 v[5], float acc) {
#pragma unroll
    for (int q = 0; q < 5; ++q) {
        acc = fmaf(w[q].x, v[q].x, acc);
        acc = fmaf(w[q].y, v[q].y, acc);
        acc = fmaf(w[q].z, v[q].z, acc);
        acc = fmaf(w[q].w, v[q].w, acc);
    }
    return acc;
}

__global__ __launch_bounds__(64)
__attribute__((amdgpu_waves_per_eu(1, 1)))
void rnn_fused(const float* __restrict__ x,      // [1024][2048][2]
               const float* __restrict__ ws,     // staged weights/bias
               float* __restrict__ out)          // [1024][2048][2]
{
    __shared__ __align__(16) float As[LDSW];     // 2560 B

    const int lane = threadIdx.x;
    const int blk  = blockIdx.x;

    const bool is_x = (lane >= 62);
    const int  c    = is_x ? (lane - 62) : (lane >= 31 ? 1 : 0);
    const int  role = is_x ? 30 : (lane - 31 * c);       // 0..30
    const int  l    = role / 5;                           // 0..6 (6 = head)
    const int  g    = role % 5;                           // head -> g=0
    const bool is_layer = (role < 30);
    const bool is_head  = (!is_x) && (role == 30);
    const int  bg   = blk * 2 + c;                        // global batch index

    // ---- uniform register-resident weights: 4 rows x (20 wh + 20 wi) ----
    float4 wh[4][5], wi[4][5];
    {
        const float4* ph = (const float4*)(ws + WS_WH + (l * 20 + 4 * g) * 20);
        const float4* pi = (const float4*)(ws + WS_WI + (l * 20 + 4 * g) * 20);
#pragma unroll
        for (int e = 0; e < 4; ++e)
#pragma unroll
            for (int q = 0; q < 5; ++q) {
                wh[e][q] = ph[e * 5 + q];
                wi[e][q] = pi[e * 5 + q];
            }
    }
    const float4 bt = *(const float4*)(ws + WS_BIAS + role * 4);

    // ---- LDS zero (h(-1)=0; x-slot pad + zero-slot stay 0) ----
    // Single wave: program order + in-order DS pipe = no barrier needed.
    for (int i = lane; i < LDSW; i += 64) As[i] = 0.f;

    // x prologue: x[0] into parity-1 (read at s=0); ring regs hold x[1], x[2]
    const float2* xp = (const float2*)x;
    float2 xA = make_float2(0.f, 0.f), xB = make_float2(0.f, 0.f);
    if (is_x) {
        *(float2*)&As[PARW + c * CBATCH] = xp[bg];
        xA = xp[(size_t)1 * BB + bg];    // written at even step s (as x[s+1])
        xB = xp[(size_t)2 * BB + bg];    // written at odd step s+1
    }

    const int ioff = l * 20;             // input slot (head: slot 6 = h5)
    const int hoff = (l + 1) * 20;       // recurrent slot (head: slot 7 = zeros)
    const int woff = hoff + 4 * g;
    float2* const op = (float2*)out;

    auto step = [&](int s, float* rbuf, float* wbuf, float2& xcur) {
        const float* rb = rbuf + c * CBATCH;
        const float4* hp = (const float4*)(rb + hoff);
        const float4* ip = (const float4*)(rb + ioff);
        float4 hq[5], iq[5];
#pragma unroll
        for (int q = 0; q < 5; ++q) { hq[q] = hp[q]; iq[q] = ip[q]; }

        const float a0 = dot5(wh[0], hq, bt.x) + dot5(wi[0], iq, 0.f);
        const float a1 = dot5(wh[1], hq, bt.y) + dot5(wi[1], iq, 0.f);
        const float a2 = dot5(wh[2], hq, bt.z) + dot5(wi[2], iq, 0.f);
        const float a3 = dot5(wh[3], hq, bt.w) + dot5(wi[3], iq, 0.f);

        if (is_layer) {
            if ((unsigned)(s - l) < TT) {                 // t in [0,1023]
                float4 r;
                r.x = fmaxf(a0, 0.f);
                r.y = fmaxf(a1, 0.f);
                r.z = fmaxf(a2, 0.f);
                r.w = fmaxf(a3, 0.f);
                *(float4*)(wbuf + c * CBATCH + woff) = r;
            }
        } else if (is_head) {
            if (s >= 6) {
                const float mx  = fmaxf(a0, a1);
                const float lse = mx + __logf(__expf(a0 - mx) + __expf(a1 - mx));
                op[(size_t)(s - 6) * BB + bg] = make_float2(a0 - lse, a1 - lse);
            }
        } else {
            // publish x[s+1]; reload this register with x[s+3] (consumed at s+2)
            if (s + 1 < TT) *(float2*)(wbuf + c * CBATCH) = xcur;
            int tl = s + 3; if (tl > TT - 1) tl = TT - 1;
            xcur = xp[(size_t)tl * BB + bg];
        }
    };

    float* const buf0 = As;          // parity 0
    float* const buf1 = As + PARW;   // parity 1
    for (int s = 0; s < NSTEPS; s += 2) {
        step(s,     buf1, buf0, xA); // even: read parity1, write parity0
        step(s + 1, buf0, buf1, xB); // odd : read parity0, write parity1
    }
}

extern "C" void kernel_launch(void* const* d_in, const int* in_sizes, int n_in,
                              void* d_out, int out_size, void* d_ws, size_t ws_size,
                              hipStream_t stream) {
    const float* x    = (const float*)d_in[0];
    const float* Wih0 = (const float*)d_in[1];
    const float* Wih  = (const float*)d_in[2];
    const float* Whh  = (const float*)d_in[3];
    const float* bih  = (const float*)d_in[4];
    const float* bhh  = (const float*)d_in[5];
    const float* fcw  = (const float*)d_in[6];
    const float* fcb  = (const float*)d_in[7];
    float* out = (float*)d_out;
    float* ws  = (float*)d_ws;

    stage_ws<<<dim3(3), dim3(1024), 0, stream>>>(Wih0, Wih, Whh, bih, bhh, fcw, fcb, ws);
    rnn_fused<<<dim3(1024), dim3(64), 0, stream>>>(x, ws, out);
}

// Round 8
// 649.319 us; speedup vs baseline: 1.0243x; 1.0243x over previous
//
#include <hip/hip_runtime.h>
#include <math.h>

// RNN_197568496340: 6-layer ReLU RNN (T=1024,B=2048,IN=2,H=20) + FC(20->2) + log_softmax.
//
// R8 = R7 + inline-asm VGPR pinning of the weights.
//  - R7 evidence: VGPR=132, FETCH 65.6MB (= ~49MB scratch leak): the compiler
//    sank/spilled the 160 loop-invariant weight floats instead of keeping them
//    live. waves_per_eu raised the budget but not the sinking heuristic.
//  - Fix: asm volatile("" : "+v"(w)) after init loads. Pinned values are
//    opaque (non-rematerializable, unsinkable) and "v" forbids AGPR parking.
//  - Tiling (unchanged from R7): 1024 single-wave blocks, lane = (role 0..30,
//    c 0..1) with 4 neuron rows/lane; head = role 30 (uniform pseudo-layer,
//    zero recurrent slot); lanes 62/63 stream x with a 2-register parity ring.
//    4 waves/CU = 1/SIMD -> 512-reg budget for ~220 live regs.

#define TT 1024
#define BB 2048
#define HH 20
#define SLOTW 20
#define CBATCH 160              // words per (parity, c): 8 slots * 20
#define PARW 320                // words per parity
#define LDSW 640
#define NSTEPS (TT + 6)         // 1030, even

// ws layout (floats)
#define WS_WH   0               // WH_pad [7][20][20]: l=0..5 Whh, l=6 zeros
#define WS_WI   2800            // WI_pad [7][20][20]: l=0 Wih0 padded, 1..5 Wih, 6 fcw padded
#define WS_BIAS 5600            // Bias   [32][4]: role<30 bih+bhh, 30 fcb-padded, 31 zeros

__global__ void stage_ws(const float* __restrict__ Wih0,
                         const float* __restrict__ Wih,
                         const float* __restrict__ Whh,
                         const float* __restrict__ bih,
                         const float* __restrict__ bhh,
                         const float* __restrict__ fcw,
                         const float* __restrict__ fcb,
                         float* __restrict__ ws) {
    const int i = threadIdx.x + blockIdx.x * blockDim.x;
    if (i < 2800) {
        const int l = i / 400, r = i % 400, j = r / 20, k = r % 20;
        ws[WS_WH + i] = (l < 6) ? Whh[l * 400 + r] : 0.f;
        float v;
        if (l == 0)     v = (k < 2) ? Wih0[j * 2 + k] : 0.f;
        else if (l < 6) v = Wih[(l - 1) * 400 + r];
        else            v = (j < 2) ? fcw[j * 20 + k] : 0.f;
        ws[WS_WI + i] = v;
    }
    if (i < 128) {
        const int role = i >> 2, e = i & 3;
        float v = 0.f;
        if (role < 30) {
            const int l = role / 5, jj = 4 * (role % 5) + e;
            v = bih[l * 20 + jj] + bhh[l * 20 + jj];
        } else if (role == 30) {
            v = (e < 2) ? fcb[e] : 0.f;
        }
        ws[WS_BIAS + i] = v;
    }
}

__device__ __forceinline__ void pin4(float4& v) {
    asm volatile("" : "+v"(v.x), "+v"(v.y), "+v"(v.z), "+v"(v.w));
}

__device__ __forceinline__ float dot5(const float4 w[5], const float4 v[5], float acc) {
#pragma unroll
    for (int q = 0; q < 5; ++q) {
        acc = fmaf(w[q].x, v[q].x, acc);
        acc = fmaf(w[q].y, v[q].y, acc);
        acc = fmaf(w[q].z, v[q].z, acc);
        acc = fmaf(w[q].w, v[q].w, acc);
    }
    return acc;
}

__global__ __launch_bounds__(64)
__attribute__((amdgpu_waves_per_eu(1, 1)))
void rnn_fused(const float* __restrict__ x,      // [1024][2048][2]
               const float* __restrict__ ws,     // staged weights/bias
               float* __restrict__ out)          // [1024][2048][2]
{
    __shared__ __align__(16) float As[LDSW];     // 2560 B

    const int lane = threadIdx.x;
    const int blk  = blockIdx.x;

    const bool is_x = (lane >= 62);
    const int  c    = is_x ? (lane - 62) : (lane >= 31 ? 1 : 0);
    const int  role = is_x ? 30 : (lane - 31 * c);       // 0..30
    const int  l    = role / 5;                           // 0..6 (6 = head)
    const int  g    = role % 5;                           // head -> g=0
    const bool is_layer = (role < 30);
    const bool is_head  = (!is_x) && (role == 30);
    const int  bg   = blk * 2 + c;                        // global batch index

    // ---- register-resident weights: 4 rows x (20 wh + 20 wi), asm-pinned ----
    float4 wh[4][5], wi[4][5];
    {
        const float4* ph = (const float4*)(ws + WS_WH + (l * 20 + 4 * g) * 20);
        const float4* pi = (const float4*)(ws + WS_WI + (l * 20 + 4 * g) * 20);
#pragma unroll
        for (int e = 0; e < 4; ++e)
#pragma unroll
            for (int q = 0; q < 5; ++q) {
                wh[e][q] = ph[e * 5 + q];
                wi[e][q] = pi[e * 5 + q];
            }
    }
    float4 bt = *(const float4*)(ws + WS_BIAS + role * 4);
#pragma unroll
    for (int e = 0; e < 4; ++e)
#pragma unroll
        for (int q = 0; q < 5; ++q) { pin4(wh[e][q]); pin4(wi[e][q]); }
    pin4(bt);

    // ---- LDS zero (h(-1)=0; x-slot pad + zero-slot stay 0) ----
    // Single wave: program order + in-order DS pipe = no barrier needed.
    for (int i = lane; i < LDSW; i += 64) As[i] = 0.f;

    // x prologue: x[0] into parity-1 (read at s=0); ring regs hold x[1], x[2]
    const float2* xp = (const float2*)x;
    float2 xA = make_float2(0.f, 0.f), xB = make_float2(0.f, 0.f);
    if (is_x) {
        *(float2*)&As[PARW + c * CBATCH] = xp[bg];
        xA = xp[(size_t)1 * BB + bg];    // published at even steps (as x[s+1])
        xB = xp[(size_t)2 * BB + bg];    // published at odd steps
    }

    const int ioff = l * 20;             // input slot (head: slot 6 = h5)
    const int hoff = (l + 1) * 20;       // recurrent slot (head: slot 7 = zeros)
    const int woff = hoff + 4 * g;
    float2* const op = (float2*)out;

    auto step = [&](int s, float* rbuf, float* wbuf, float2& xcur) {
        const float* rb = rbuf + c * CBATCH;
        const float4* hp = (const float4*)(rb + hoff);
        const float4* ip = (const float4*)(rb + ioff);
        float4 hq[5], iq[5];
#pragma unroll
        for (int q = 0; q < 5; ++q) { hq[q] = hp[q]; iq[q] = ip[q]; }

        const float a0 = dot5(wh[0], hq, bt.x) + dot5(wi[0], iq, 0.f);
        const float a1 = dot5(wh[1], hq, bt.y) + dot5(wi[1], iq, 0.f);
        const float a2 = dot5(wh[2], hq, bt.z) + dot5(wi[2], iq, 0.f);
        const float a3 = dot5(wh[3], hq, bt.w) + dot5(wi[3], iq, 0.f);

        if (is_layer) {
            if ((unsigned)(s - l) < TT) {                 // t in [0,1023]
                float4 r;
                r.x = fmaxf(a0, 0.f);
                r.y = fmaxf(a1, 0.f);
                r.z = fmaxf(a2, 0.f);
                r.w = fmaxf(a3, 0.f);
                *(float4*)(wbuf + c * CBATCH + woff) = r;
            }
        } else if (is_head) {
            if (s >= 6) {
                const float mx  = fmaxf(a0, a1);
                const float lse = mx + __logf(__expf(a0 - mx) + __expf(a1 - mx));
                op[(size_t)(s - 6) * BB + bg] = make_float2(a0 - lse, a1 - lse);
            }
        } else {
            // publish x[s+1]; reload this register with x[s+3] (consumed s+2)
            if (s + 1 < TT) *(float2*)(wbuf + c * CBATCH) = xcur;
            int tl = s + 3; if (tl > TT - 1) tl = TT - 1;
            xcur = xp[(size_t)tl * BB + bg];
        }
    };

    float* const buf0 = As;          // parity 0
    float* const buf1 = As + PARW;   // parity 1
    for (int s = 0; s < NSTEPS; s += 2) {
        step(s,     buf1, buf0, xA); // even: read parity1, write parity0
        step(s + 1, buf0, buf1, xB); // odd : read parity0, write parity1
    }
}

extern "C" void kernel_launch(void* const* d_in, const int* in_sizes, int n_in,
                              void* d_out, int out_size, void* d_ws, size_t ws_size,
                              hipStream_t stream) {
    const float* x    = (const float*)d_in[0];
    const float* Wih0 = (const float*)d_in[1];
    const float* Wih  = (const float*)d_in[2];
    const float* Whh  = (const float*)d_in[3];
    const float* bih  = (const float*)d_in[4];
    const float* bhh  = (const float*)d_in[5];
    const float* fcw  = (const float*)d_in[6];
    const float* fcb  = (const float*)d_in[7];
    float* out = (float*)d_out;
    float* ws  = (float*)d_ws;

    stage_ws<<<dim3(3), dim3(1024), 0, stream>>>(Wih0, Wih, Whh, bih, bhh, fcw, fcb, ws);
    rnn_fused<<<dim3(1024), dim3(64), 0, stream>>>(x, ws, out);
}